// Round 3
// baseline (1966.307 us; speedup 1.0000x reference)
//
#include <hip/hip_runtime.h>
#include <math.h>

typedef unsigned short u16;
typedef unsigned int   u32;
typedef __attribute__((ext_vector_type(8))) short bf16x8;
typedef __attribute__((ext_vector_type(4))) float f32x4;

typedef const void __attribute__((address_space(1))) gv1_t;
typedef void       __attribute__((address_space(3))) lv3_t;
#define GLL(g, l) __builtin_amdgcn_global_load_lds((gv1_t*)(g), (lv3_t*)(l), 16, 0, 0)

__device__ __forceinline__ u16 f2b(float x) {
    union { float f; u32 u; } v; v.f = x;
    u32 r = v.u + 0x7FFFu + ((v.u >> 16) & 1u);
    return (u16)(r >> 16);
}
__device__ __forceinline__ float b2f(u32 x) {
    union { u32 u; float f; } v; v.u = x << 16;
    return v.f;
}

// ---------------------------------------------------------------------------
// prep: f32 -> bf16 convert (adj)
// ---------------------------------------------------------------------------
__global__ void cvt_f32_bf16(const float* __restrict__ a, u16* __restrict__ o, int n) {
    for (int i = (blockIdx.x * 256 + threadIdx.x) * 4; i < n; i += gridDim.x * 256 * 4) {
        float4 v = *(const float4*)&a[i];
        uint2 pk;
        pk.x = (u32)f2b(v.x) | ((u32)f2b(v.y) << 16);
        pk.y = (u32)f2b(v.z) | ((u32)f2b(v.w) << 16);
        *(uint2*)&o[i] = pk;
    }
}

// ---------------------------------------------------------------------------
// prep: x = data + temb + semb; write Xn [b][t][n][c] bf16 and XT [(b,c)][t*1024+n]
// ---------------------------------------------------------------------------
__global__ void prep_x(const float* __restrict__ data, const float* __restrict__ temb,
                       const float* __restrict__ semb, u16* __restrict__ Xn, u16* __restrict__ XT) {
    const int n0 = blockIdx.x * 64, t = blockIdx.y, b = blockIdx.z;
    const int tid = threadIdx.x;
    __shared__ u16 lt[64][66];
#pragma unroll
    for (int p = 0; p < 4; p++) {
        int n = p * 16 + (tid >> 4);
        int c = (tid & 15) * 4;
        size_t gi = ((size_t)(b * 12 + t) * 1024 + n0 + n) * 64 + c;
        float4 v  = *(const float4*)&data[gi];
        float4 tv = *(const float4*)&temb[t * 64 + c];
        float4 sv = *(const float4*)&semb[(n0 + n) * 64 + c];
        u16 u0 = f2b(v.x + tv.x + sv.x);
        u16 u1 = f2b(v.y + tv.y + sv.y);
        u16 u2 = f2b(v.z + tv.z + sv.z);
        u16 u3 = f2b(v.w + tv.w + sv.w);
        uint2 pk; pk.x = (u32)u0 | ((u32)u1 << 16); pk.y = (u32)u2 | ((u32)u3 << 16);
        *(uint2*)&Xn[gi] = pk;
        lt[n][c + 0] = u0; lt[n][c + 1] = u1; lt[n][c + 2] = u2; lt[n][c + 3] = u3;
    }
    __syncthreads();
    const int c = tid >> 2, q = tid & 3;
    u16 u[16];
#pragma unroll
    for (int i = 0; i < 16; i++) u[i] = lt[q * 16 + i][c];
    size_t xo = ((size_t)(b * 64 + c)) * 12288 + (size_t)t * 1024 + n0 + q * 16;
    uint4 p0, p1;
    p0.x = (u32)u[0] | ((u32)u[1] << 16);  p0.y = (u32)u[2] | ((u32)u[3] << 16);
    p0.z = (u32)u[4] | ((u32)u[5] << 16);  p0.w = (u32)u[6] | ((u32)u[7] << 16);
    p1.x = (u32)u[8] | ((u32)u[9] << 16);  p1.y = (u32)u[10] | ((u32)u[11] << 16);
    p1.z = (u32)u[12] | ((u32)u[13] << 16); p1.w = (u32)u[14] | ((u32)u[15] << 16);
    *(uint4*)&XT[xo] = p0;
    *(uint4*)&XT[xo + 8] = p1;
}

// ---------------------------------------------------------------------------
// prep: fc_w [27][64][128] -> Wt [27][128][64] bf16 ; conv weights -> Wc bf16
// ---------------------------------------------------------------------------
__global__ void prep_w(const float* __restrict__ fcw, const float* __restrict__ cwl,
                       const float* __restrict__ cwr, u16* __restrict__ Wt, u16* __restrict__ Wc) {
    const int blk = blockIdx.x, tid = threadIdx.x;
    if (blk < 27) {
        const float* src = fcw + (size_t)blk * 64 * 128;
        u16* dst = Wt + (size_t)blk * 128 * 64;
        for (int e = tid; e < 8192; e += 256) {
            int c = e >> 7, f = e & 127;
            dst[f * 64 + c] = f2b(src[c * 128 + f]);
        }
    } else {
        for (int e = tid; e < 16384; e += 256) {
            int o = e >> 7, k = e & 127;
            float v = (o < 64) ? cwl[(o * 64 + (k & 63)) * 2 + (k >> 6)]
                               : cwr[((o - 64) * 64 + (k & 63)) * 2 + (k >> 6)];
            Wc[o * 128 + k] = f2b(v);
        }
    }
}

// ---------------------------------------------------------------------------
// gated dilated conv as GEMM (unchanged)
// ---------------------------------------------------------------------------
__global__ __launch_bounds__(256) void dconv_gemm(
    const u16* __restrict__ Xn, const u16* __restrict__ Wc,
    const float* __restrict__ cbl, const float* __restrict__ cbr,
    float* __restrict__ out) {
    const int n0 = blockIdx.x * 128, t = blockIdx.y, b = blockIdx.z;
    const int tid = threadIdx.x, lane = tid & 63, wid = tid >> 6;
    __shared__ u16 alds[2][128 * 32];
    const u16* base0 = Xn + (size_t)(b * 12 + t) * 1024 * 64;
    const u16* base3 = Xn + (size_t)(b * 12 + t + 3) * 1024 * 64;

    auto stage = [&](int buf, int kt) {
        int k0 = kt * 32;
#pragma unroll
        for (int q = 0; q < 2; q++) {
            int r = wid * 32 + q * 16 + (lane >> 2);
            int k = k0 + (lane & 3) * 8;
            const u16* gs = (k < 64) ? base0 + (size_t)(n0 + r) * 64 + k
                                     : base3 + (size_t)(n0 + r) * 64 + (k - 64);
            GLL(gs, &alds[buf][(wid * 32 + q * 16) * 32]);
        }
    };

    f32x4 acc[2][8] = {};
    stage(0, 0);
    __syncthreads();
    const int a_off = (wid * 32 + (lane & 15)) * 32 + (lane >> 4) * 8;
    for (int kt = 0; kt < 4; kt++) {
        int cur = kt & 1;
        if (kt < 3) stage(cur ^ 1, kt + 1);
        bf16x8 af[2];
#pragma unroll
        for (int m = 0; m < 2; m++) af[m] = *(const bf16x8*)&alds[cur][a_off + m * 16 * 32];
#pragma unroll
        for (int n = 0; n < 8; n++) {
            bf16x8 bq = *(const bf16x8*)&Wc[(n * 16 + (lane & 15)) * 128 + kt * 32 + (lane >> 4) * 8];
#pragma unroll
            for (int m = 0; m < 2; m++)
                acc[m][n] = __builtin_amdgcn_mfma_f32_16x16x32_bf16(af[m], bq, acc[m][n], 0, 0, 0);
        }
        __syncthreads();
    }
#pragma unroll
    for (int m = 0; m < 2; m++) {
#pragma unroll
        for (int n = 0; n < 4; n++) {
            int fp = n * 16 + (lane & 15);
            float b1 = cbl[fp], b2 = cbr[fp];
#pragma unroll
            for (int j = 0; j < 4; j++) {
                int row = wid * 32 + m * 16 + (lane >> 4) * 4 + j;
                float gl = acc[m][n][j] + b1;
                float gr = acc[m][n + 4][j] + b2;
                out[((size_t)(b * 9 + t) * 1024 + n0 + row) * 64 + fp] =
                    (1.0f / (1.0f + expf(-gl))) * tanhf(gr);
            }
        }
    }
}

// ---------------------------------------------------------------------------
// 8-phase 256x256 agg GEMM with FUSED GLU epilogue.
// Main loop: Y[(b,c)][v] = sum_w A[(b,c)][w] * adj[v][w]  (in acc, f32)
// Epilogue:  P[(b,f)][v] = GLU(W^T Y + bias), written directly to P.
// STAGE==ks: 0 -> A from XT (windowed), 1 -> A = P1.
// ---------------------------------------------------------------------------
#define SB() do { __builtin_amdgcn_sched_barrier(0); __builtin_amdgcn_s_barrier(); __builtin_amdgcn_sched_barrier(0); } while (0)
#define GATE() asm volatile("s_waitcnt vmcnt(4)" ::: "memory")
#define GATE0() asm volatile("s_waitcnt vmcnt(0)" ::: "memory")

template <int STAGE>
__global__ __launch_bounds__(512, 2) void agg_gemm8(
    const u16* __restrict__ A, const u16* __restrict__ Bt,
    const u16* __restrict__ Wt, const float* __restrict__ fcb,
    u16* __restrict__ P, int win0) {
    const int bx = blockIdx.x, by = blockIdx.y, z = blockIdx.z;
    const int tid = threadIdx.x, lane = tid & 63, wid = tid >> 6;
    const int wr = wid >> 2, wc = wid & 3;
    const int rowBase = by * 256, colBase = bx * 256;
    const int win = win0 + z;
    __shared__ u16 lds[2][2][2][128 * 64];  // 128 KiB
    __shared__ float biasSm[128];
    if (tid < 128) biasSm[tid] = fcb[(win * 3 + STAGE) * 128 + tid];
    const u16* Az = (STAGE == 0) ? A : (A + (size_t)z * 2048 * 4096);

    const int srow = lane >> 3;
    const int skb  = 8 * ((lane & 7) ^ srow);

    auto stageA = [&](int buf, int half, int s, int kt) {
        if (kt >= 64) return;
        int r0 = s * 64 + wid * 8;
        int row_g = rowBase + half * 128 + r0 + srow;
        const u16* src;
        if (STAGE == 0) {
            int k = kt * 64 + skb;
            src = Az + (size_t)row_g * 12288 + (size_t)(win + (k >> 10)) * 1024 + (k & 1023);
        } else {
            src = Az + (size_t)row_g * 4096 + kt * 64 + skb;
        }
        GLL(src, &lds[buf][0][half][r0 * 64]);
    };
    auto stageB = [&](int buf, int half, int s, int kt) {
        if (kt >= 64) return;
        int r0 = s * 64 + wid * 8;
        int col_g = colBase + half * 128 + r0 + srow;
        GLL(Bt + (size_t)col_g * 4096 + kt * 64 + skb, &lds[buf][1][half][r0 * 64]);
    };
#define STH_A(buf, half, kt) do { stageA(buf, half, 0, kt); stageA(buf, half, 1, kt); } while (0)
#define STH_B(buf, half, kt) do { stageB(buf, half, 0, kt); stageB(buf, half, 1, kt); } while (0)

    f32x4 acc[8][4] = {};
    bf16x8 aF[4][2], bF[4][2];

#define READ_A(buf, mb)                                                       \
    _Pragma("unroll") for (int mm = 0; mm < 4; mm++)                          \
    _Pragma("unroll") for (int kk = 0; kk < 2; kk++) {                        \
        int r = ((mb) + mm) * 16 + (lane & 15);                               \
        int hw = (kk * 32 + (lane >> 4) * 8) ^ ((r & 7) << 3);                \
        aF[mm][kk] = *(const bf16x8*)&lds[buf][0][wr][r * 64 + hw];           \
    }
#define READ_B(buf, nb)                                                       \
    _Pragma("unroll") for (int nn = 0; nn < 2; nn++)                          \
    _Pragma("unroll") for (int kk = 0; kk < 2; kk++) {                        \
        int r = (wc & 1) * 64 + ((nb) + nn) * 16 + (lane & 15);               \
        int hw = (kk * 32 + (lane >> 4) * 8) ^ ((r & 7) << 3);                \
        bF[(nb) + nn][kk] = *(const bf16x8*)&lds[buf][1][wc >> 1][r * 64 + hw]; \
    }
#define MFMA8(mb, nb)                                                         \
    __builtin_amdgcn_s_setprio(1);                                            \
    _Pragma("unroll") for (int mm = 0; mm < 4; mm++)                          \
    _Pragma("unroll") for (int nn = 0; nn < 2; nn++)                          \
    _Pragma("unroll") for (int kk = 0; kk < 2; kk++)                          \
        acc[(mb) + mm][(nb) + nn] = __builtin_amdgcn_mfma_f32_16x16x32_bf16(  \
            aF[mm][kk], bF[(nb) + nn][kk], acc[(mb) + mm][(nb) + nn], 0, 0, 0); \
    __builtin_amdgcn_s_setprio(0);

    // prologue: tile0 -> buf0; tile1 -> buf1 (B0,A0)
    STH_B(0, 0, 0); STH_A(0, 0, 0); STH_B(0, 1, 0); STH_A(0, 1, 0);
    STH_B(1, 0, 1); STH_A(1, 0, 1);
    GATE();
    SB();

    for (int i = 0; i < 31; i++) {
        int t1 = 2 * i + 1, t2 = 2 * i + 2, t3 = 2 * i + 3;
        // ---- K-tile 2i in buf0 ----
        READ_A(0, 0); READ_B(0, 0);
        STH_B(1, 1, t1);
        SB(); MFMA8(0, 0); SB();

        READ_B(0, 2);
        STH_A(1, 1, t1);
        SB(); MFMA8(0, 2); SB();

        READ_A(0, 4);
        STH_B(0, 0, t2);
        SB(); MFMA8(4, 0); SB();

        STH_A(0, 0, t2);
        SB(); MFMA8(4, 2); GATE(); SB();   // tile 2i+1 fully landed

        // ---- K-tile 2i+1 in buf1 ----
        READ_A(1, 0); READ_B(1, 0);
        STH_B(0, 1, t2);
        SB(); MFMA8(0, 0); SB();

        READ_B(1, 2);
        STH_A(0, 1, t2);
        SB(); MFMA8(0, 2); SB();

        READ_A(1, 4);
        STH_B(1, 0, t3);
        SB(); MFMA8(4, 0); SB();

        STH_A(1, 0, t3);
        SB(); MFMA8(4, 2); GATE(); SB();   // tile 2i+2 fully landed
    }

    // ---- peeled tail: K-tile 62 (buf0), finish staging 63; K-tile 63 (buf1)
    READ_A(0, 0); READ_B(0, 0);
    STH_B(1, 1, 63);
    SB(); MFMA8(0, 0); SB();

    READ_B(0, 2);
    STH_A(1, 1, 63);
    SB(); MFMA8(0, 2); SB();

    READ_A(0, 4);
    SB(); MFMA8(4, 0); SB();

    SB(); MFMA8(4, 2); GATE0(); SB();      // all loads drained

    READ_A(1, 0); READ_B(1, 0);
    SB(); MFMA8(0, 0); SB();
    READ_B(1, 2);
    SB(); MFMA8(0, 2); SB();
    READ_A(1, 4);
    SB(); MFMA8(4, 0); SB();
    MFMA8(4, 2);

    // ================= fused GLU epilogue =================
    __syncthreads();  // all MFMA/ds reads done; LDS reusable
    u16* YT = &lds[0][0][0][0];  // [4 batch][256 v][64 c] bf16, 16B-granule swizzled

    // stage 1: acc -> YT
#pragma unroll
    for (int m = 0; m < 8; m++) {
        int bi = wr * 2 + (m >> 2);
        int c0 = (m & 3) * 16 + (lane >> 4) * 4;
#pragma unroll
        for (int n = 0; n < 4; n++) {
            int v = wc * 64 + n * 16 + (lane & 15);
            ushort4 pk;
            pk.x = f2b(acc[m][n][0]); pk.y = f2b(acc[m][n][1]);
            pk.z = f2b(acc[m][n][2]); pk.w = f2b(acc[m][n][3]);
            int addr = bi * 16384 + v * 64 + (((c0 >> 3) ^ (v & 7)) << 3) + (c0 & 7);
            *(ushort4*)&YT[addr] = pk;
        }
    }
    __syncthreads();

    // stage 2: P[f][v] = GLU(W^T Y + bias)
    const int bi2 = wid >> 1, h = wid & 1;
    const u16* Wl = Wt + (size_t)(win * 3 + STAGE) * 8192;
    u16* Pz = P + (size_t)z * 2048 * 4096;
#pragma unroll
    for (int vq = 0; vq < 2; vq++) {
        f32x4 acc2[8][4] = {};
        bf16x8 bq2[4][2];
#pragma unroll
        for (int nt = 0; nt < 4; nt++) {
            int v = h * 128 + vq * 64 + nt * 16 + (lane & 15);
#pragma unroll
            for (int kk = 0; kk < 2; kk++) {
                int g = kk * 4 + (lane >> 4);
                bq2[nt][kk] = *(const bf16x8*)&YT[bi2 * 16384 + v * 64 + ((g ^ (v & 7)) << 3)];
            }
        }
#pragma unroll
        for (int fi = 0; fi < 8; fi++) {
            bf16x8 aw[2];
#pragma unroll
            for (int kk = 0; kk < 2; kk++)
                aw[kk] = *(const bf16x8*)&Wl[(fi * 16 + (lane & 15)) * 64 + kk * 32 + (lane >> 4) * 8];
#pragma unroll
            for (int nt = 0; nt < 4; nt++)
#pragma unroll
                for (int kk = 0; kk < 2; kk++)
                    acc2[fi][nt] = __builtin_amdgcn_mfma_f32_16x16x32_bf16(
                        aw[kk], bq2[nt][kk], acc2[fi][nt], 0, 0, 0);
        }
#pragma unroll
        for (int fi = 0; fi < 4; fi++) {
#pragma unroll
            for (int j = 0; j < 4; j++) {
                int f = fi * 16 + (lane >> 4) * 4 + j;
                float b1 = biasSm[f], b2v = biasSm[f + 64];
#pragma unroll
                for (int nt = 0; nt < 4; nt++) {
                    float g1 = acc2[fi][nt][j] + b1;
                    float g2 = acc2[fi + 4][nt][j] + b2v;
                    float val = g1 / (1.0f + expf(-g2));
                    int row = rowBase + bi2 * 64 + f;
                    int col = colBase + h * 128 + vq * 64 + nt * 16 + (lane & 15);
                    Pz[(size_t)row * 4096 + col] = f2b(val);
                }
            }
        }
    }
#undef READ_A
#undef READ_B
#undef MFMA8
#undef STH_A
#undef STH_B
}

// ---------------------------------------------------------------------------
// 128x128 2-phase agg GEMM with fused GLU — layer 3 (N=1024, vbase=1024, ks=2)
// ---------------------------------------------------------------------------
__global__ __launch_bounds__(256) void agg_small_f(
    const u16* __restrict__ A, const u16* __restrict__ Bt,
    const u16* __restrict__ Wt, const float* __restrict__ fcb,
    u16* __restrict__ P3, int win0) {
    const int bx = blockIdx.x, by = blockIdx.y, z = blockIdx.z;
    const int tid = threadIdx.x, lane = tid & 63, wid = tid >> 6;
    const int wr = wid >> 1, wc = wid & 1;
    const int row0 = by * 128;
    const int win = win0 + z;
    __shared__ u16 lds[2][2][128 * 32];  // 32 KiB
    __shared__ float biasSm[128];
    if (tid < 128) biasSm[tid] = fcb[(win * 3 + 2) * 128 + tid];
    const u16* Az = A + (size_t)z * 2048 * 4096;
    const int skk = (lane & 3) * 8;

    auto stage = [&](int buf, int kt) {
        int k0 = kt * 32;
#pragma unroll
        for (int q = 0; q < 2; q++) {
            int r = wid * 32 + q * 16 + (lane >> 2);
            GLL(Az + (size_t)(row0 + r) * 4096 + k0 + skk, &lds[buf][0][(wid * 32 + q * 16) * 32]);
            int n = 1024 + bx * 128 + r;
            GLL(Bt + (size_t)n * 4096 + k0 + skk, &lds[buf][1][(wid * 32 + q * 16) * 32]);
        }
    };

    f32x4 acc[4][4] = {};
    stage(0, 0);
    __syncthreads();
    const int a_off = (wr * 64 + (lane & 15)) * 32 + (lane >> 4) * 8;
    const int b_off = (wc * 64 + (lane & 15)) * 32 + (lane >> 4) * 8;
    for (int kt = 0; kt < 128; kt++) {
        int cur = kt & 1;
        if (kt < 127) stage(cur ^ 1, kt + 1);
        bf16x8 af[4], bq[4];
#pragma unroll
        for (int m = 0; m < 4; m++) af[m] = *(const bf16x8*)&lds[cur][0][a_off + m * 16 * 32];
#pragma unroll
        for (int n = 0; n < 4; n++) bq[n] = *(const bf16x8*)&lds[cur][1][b_off + n * 16 * 32];
#pragma unroll
        for (int m = 0; m < 4; m++)
#pragma unroll
            for (int n = 0; n < 4; n++)
                acc[m][n] = __builtin_amdgcn_mfma_f32_16x16x32_bf16(af[m], bq[n], acc[m][n], 0, 0, 0);
        __syncthreads();
    }

    // ---- fused GLU epilogue (2 batches x 128 v) ----
    u16* YT = &lds[0][0][0];  // [2][128 v][64 c] swizzled
#pragma unroll
    for (int m = 0; m < 4; m++) {
        int c0 = m * 16 + (lane >> 4) * 4;
#pragma unroll
        for (int n = 0; n < 4; n++) {
            int v = wc * 64 + n * 16 + (lane & 15);
            ushort4 pk;
            pk.x = f2b(acc[m][n][0]); pk.y = f2b(acc[m][n][1]);
            pk.z = f2b(acc[m][n][2]); pk.w = f2b(acc[m][n][3]);
            int addr = wr * 8192 + v * 64 + (((c0 >> 3) ^ (v & 7)) << 3) + (c0 & 7);
            *(ushort4*)&YT[addr] = pk;
        }
    }
    __syncthreads();

    const int bi2 = wid >> 1, h = wid & 1;
    const u16* Wl = Wt + (size_t)(win * 3 + 2) * 8192;
    u16* Pz = P3 + (size_t)z * 2048 * 1024;
    f32x4 acc2[8][4] = {};
    bf16x8 bq2[4][2];
#pragma unroll
    for (int nt = 0; nt < 4; nt++) {
        int v = h * 64 + nt * 16 + (lane & 15);
#pragma unroll
        for (int kk = 0; kk < 2; kk++) {
            int g = kk * 4 + (lane >> 4);
            bq2[nt][kk] = *(const bf16x8*)&YT[bi2 * 8192 + v * 64 + ((g ^ (v & 7)) << 3)];
        }
    }
#pragma unroll
    for (int fi = 0; fi < 8; fi++) {
        bf16x8 aw[2];
#pragma unroll
        for (int kk = 0; kk < 2; kk++)
            aw[kk] = *(const bf16x8*)&Wl[(fi * 16 + (lane & 15)) * 64 + kk * 32 + (lane >> 4) * 8];
#pragma unroll
        for (int nt = 0; nt < 4; nt++)
#pragma unroll
            for (int kk = 0; kk < 2; kk++)
                acc2[fi][nt] = __builtin_amdgcn_mfma_f32_16x16x32_bf16(
                    aw[kk], bq2[nt][kk], acc2[fi][nt], 0, 0, 0);
    }
#pragma unroll
    for (int fi = 0; fi < 4; fi++) {
#pragma unroll
        for (int j = 0; j < 4; j++) {
            int f = fi * 16 + (lane >> 4) * 4 + j;
            float b1 = biasSm[f], b2v = biasSm[f + 64];
#pragma unroll
            for (int nt = 0; nt < 4; nt++) {
                float g1 = acc2[fi][nt][j] + b1;
                float g2 = acc2[fi + 4][nt][j] + b2v;
                float val = g1 / (1.0f + expf(-g2));
                int row = row0 + bi2 * 64 + f;
                int col = bx * 128 + h * 64 + nt * 16 + (lane & 15);
                Pz[(size_t)row * 1024 + col] = f2b(val);
            }
        }
    }
}

// ---------------------------------------------------------------------------
// final: out[b,win,n,f] += max(P1mid, P2mid, P3)
// ---------------------------------------------------------------------------
__global__ void final_add(const u16* __restrict__ P1, const u16* __restrict__ P2,
                          const u16* __restrict__ P3, float* __restrict__ out, int win0) {
    const int n0 = blockIdx.x * 64, b = blockIdx.y, z = blockIdx.z;
    const int win = win0 + z;
    const int tid = threadIdx.x;
    __shared__ float tl[64][65];
    {
        int f = tid >> 2, q = tid & 3;
        size_t o12 = ((size_t)z * 2048 + b * 64 + f) * 4096 + 1024 + n0 + q * 16;
        size_t o3  = ((size_t)z * 2048 + b * 64 + f) * 1024 + n0 + q * 16;
#pragma unroll
        for (int i = 0; i < 16; i += 4) {
            uint2 a  = *(const uint2*)&P1[o12 + i];
            uint2 c2 = *(const uint2*)&P2[o12 + i];
            uint2 d  = *(const uint2*)&P3[o3 + i];
            u32 av[4] = {a.x & 0xffffu, a.x >> 16, a.y & 0xffffu, a.y >> 16};
            u32 bv[4] = {c2.x & 0xffffu, c2.x >> 16, c2.y & 0xffffu, c2.y >> 16};
            u32 dv[4] = {d.x & 0xffffu, d.x >> 16, d.y & 0xffffu, d.y >> 16};
#pragma unroll
            for (int jj = 0; jj < 4; jj++)
                tl[q * 16 + i + jj][f] = fmaxf(fmaxf(b2f(av[jj]), b2f(bv[jj])), b2f(dv[jj]));
        }
    }
    __syncthreads();
    {
        int n = tid >> 2, q = tid & 3;
        size_t oo = ((size_t)(b * 9 + win) * 1024 + n0 + n) * 64 + q * 16;
#pragma unroll
        for (int i = 0; i < 16; i += 4) {
            float4 cur = *(const float4*)&out[oo + i];
            cur.x += tl[n][q * 16 + i + 0];
            cur.y += tl[n][q * 16 + i + 1];
            cur.z += tl[n][q * 16 + i + 2];
            cur.w += tl[n][q * 16 + i + 3];
            *(float4*)&out[oo + i] = cur;
        }
    }
}

// ---------------------------------------------------------------------------
extern "C" void kernel_launch(void* const* d_in, const int* in_sizes, int n_in,
                              void* d_out, int out_size, void* d_ws, size_t ws_size,
                              hipStream_t stream) {
    const float* data = (const float*)d_in[0];
    const float* adj  = (const float*)d_in[1];
    const float* temb = (const float*)d_in[2];
    const float* semb = (const float*)d_in[3];
    const float* cwl  = (const float*)d_in[4];
    const float* cbl  = (const float*)d_in[5];
    const float* cwr  = (const float*)d_in[6];
    const float* cbr  = (const float*)d_in[7];
    const float* fcw  = (const float*)d_in[8];
    const float* fcb  = (const float*)d_in[9];
    float* out = (float*)d_out;

    char* p = (char*)d_ws;
    auto alloc = [&](size_t bytes) -> char* {
        char* r = p;
        p += (bytes + 255) & ~(size_t)255;
        return r;
    };
    const size_t SZ_XT  = 2048UL * 12288 * 2;
    const size_t SZ_XN  = 32UL * 12 * 1024 * 64 * 2;
    const size_t SZ_ADJ = 4096UL * 4096 * 2;
    const size_t SZ_WT  = 27UL * 128 * 64 * 2;
    const size_t SZ_WC  = 128UL * 128 * 2;
    const size_t SZ_P12 = 2048UL * 4096 * 2;  // 16 MiB
    const size_t SZ_P3  = 2048UL * 1024 * 2;  //  4 MiB
    u16* XT   = (u16*)alloc(SZ_XT);
    u16* adjb = (u16*)alloc(SZ_ADJ);
    u16* Wt   = (u16*)alloc(SZ_WT);
    u16* Wc   = (u16*)alloc(SZ_WC);

    char* winBase = p;
    size_t avail = ws_size - (size_t)(winBase - (char*)d_ws);
    const size_t perwin = 2 * SZ_P12 + SZ_P3 + 3 * 256;
    int cap = (int)(avail / perwin);
    if (cap > 9) cap = 9;
    if (cap < 1) cap = 1;
    u16* P1 = (u16*)alloc((size_t)cap * SZ_P12);
    u16* P2 = (u16*)alloc((size_t)cap * SZ_P12);
    u16* P3 = (u16*)alloc((size_t)cap * SZ_P3);
    // Xn aliases the window-buffer region (dead before first P write)
    u16* Xn = ((size_t)cap * perwin >= SZ_XN + 256) ? (u16*)winBase : (u16*)alloc(SZ_XN);

    cvt_f32_bf16<<<4096, 256, 0, stream>>>(adj, adjb, 4096 * 4096);
    prep_x<<<dim3(16, 12, 32), 256, 0, stream>>>(data, temb, semb, Xn, XT);
    prep_w<<<28, 256, 0, stream>>>(fcw, cwl, cwr, Wt, Wc);
    dconv_gemm<<<dim3(8, 9, 32), 256, 0, stream>>>(Xn, Wc, cbl, cbr, out);

    for (int w0 = 0; w0 < 9;) {
        int cw = 9 - w0 < cap ? 9 - w0 : cap;
        agg_gemm8<0><<<dim3(16, 8, cw), 512, 0, stream>>>(XT, adjb, Wt, fcb, P1, w0);
        agg_gemm8<1><<<dim3(16, 8, cw), 512, 0, stream>>>(P1, adjb, Wt, fcb, P2, w0);
        agg_small_f<<<dim3(8, 16, cw), 256, 0, stream>>>(P2, adjb, Wt, fcb, P3, w0);
        final_add<<<dim3(16, 32, cw), 256, 0, stream>>>(P1, P2, P3, out, w0);
        w0 += cw;
    }
}

// Round 4
// 1842.426 us; speedup vs baseline: 1.0672x; 1.0672x over previous
//
#include <hip/hip_runtime.h>
#include <math.h>

typedef unsigned short u16;
typedef unsigned int   u32;
typedef __attribute__((ext_vector_type(8))) short bf16x8;
typedef __attribute__((ext_vector_type(4))) float f32x4;

typedef const void __attribute__((address_space(1))) gv1_t;
typedef void       __attribute__((address_space(3))) lv3_t;
#define GLL(g, l) __builtin_amdgcn_global_load_lds((gv1_t*)(g), (lv3_t*)(l), 16, 0, 0)

__device__ __forceinline__ u16 f2b(float x) {
    union { float f; u32 u; } v; v.f = x;
    u32 r = v.u + 0x7FFFu + ((v.u >> 16) & 1u);
    return (u16)(r >> 16);
}
__device__ __forceinline__ float b2f(u32 x) {
    union { u32 u; float f; } v; v.u = x << 16;
    return v.f;
}

// ---------------------------------------------------------------------------
// prep: f32 -> bf16 convert (adj)
// ---------------------------------------------------------------------------
__global__ void cvt_f32_bf16(const float* __restrict__ a, u16* __restrict__ o, int n) {
    for (int i = (blockIdx.x * 256 + threadIdx.x) * 4; i < n; i += gridDim.x * 256 * 4) {
        float4 v = *(const float4*)&a[i];
        uint2 pk;
        pk.x = (u32)f2b(v.x) | ((u32)f2b(v.y) << 16);
        pk.y = (u32)f2b(v.z) | ((u32)f2b(v.w) << 16);
        *(uint2*)&o[i] = pk;
    }
}

// ---------------------------------------------------------------------------
// prep: x = data + temb + semb; write Xn [b][t][n][c] bf16 and XT [(b,c)][t*1024+n]
// ---------------------------------------------------------------------------
__global__ void prep_x(const float* __restrict__ data, const float* __restrict__ temb,
                       const float* __restrict__ semb, u16* __restrict__ Xn, u16* __restrict__ XT) {
    const int n0 = blockIdx.x * 64, t = blockIdx.y, b = blockIdx.z;
    const int tid = threadIdx.x;
    __shared__ u16 lt[64][66];
#pragma unroll
    for (int p = 0; p < 4; p++) {
        int n = p * 16 + (tid >> 4);
        int c = (tid & 15) * 4;
        size_t gi = ((size_t)(b * 12 + t) * 1024 + n0 + n) * 64 + c;
        float4 v  = *(const float4*)&data[gi];
        float4 tv = *(const float4*)&temb[t * 64 + c];
        float4 sv = *(const float4*)&semb[(n0 + n) * 64 + c];
        u16 u0 = f2b(v.x + tv.x + sv.x);
        u16 u1 = f2b(v.y + tv.y + sv.y);
        u16 u2 = f2b(v.z + tv.z + sv.z);
        u16 u3 = f2b(v.w + tv.w + sv.w);
        uint2 pk; pk.x = (u32)u0 | ((u32)u1 << 16); pk.y = (u32)u2 | ((u32)u3 << 16);
        *(uint2*)&Xn[gi] = pk;
        lt[n][c + 0] = u0; lt[n][c + 1] = u1; lt[n][c + 2] = u2; lt[n][c + 3] = u3;
    }
    __syncthreads();
    const int c = tid >> 2, q = tid & 3;
    u16 u[16];
#pragma unroll
    for (int i = 0; i < 16; i++) u[i] = lt[q * 16 + i][c];
    size_t xo = ((size_t)(b * 64 + c)) * 12288 + (size_t)t * 1024 + n0 + q * 16;
    uint4 p0, p1;
    p0.x = (u32)u[0] | ((u32)u[1] << 16);  p0.y = (u32)u[2] | ((u32)u[3] << 16);
    p0.z = (u32)u[4] | ((u32)u[5] << 16);  p0.w = (u32)u[6] | ((u32)u[7] << 16);
    p1.x = (u32)u[8] | ((u32)u[9] << 16);  p1.y = (u32)u[10] | ((u32)u[11] << 16);
    p1.z = (u32)u[12] | ((u32)u[13] << 16); p1.w = (u32)u[14] | ((u32)u[15] << 16);
    *(uint4*)&XT[xo] = p0;
    *(uint4*)&XT[xo + 8] = p1;
}

// ---------------------------------------------------------------------------
// prep: fc_w [27][64][128] -> Wt [27][128][64] bf16 ; conv weights -> Wc bf16
// ---------------------------------------------------------------------------
__global__ void prep_w(const float* __restrict__ fcw, const float* __restrict__ cwl,
                       const float* __restrict__ cwr, u16* __restrict__ Wt, u16* __restrict__ Wc) {
    const int blk = blockIdx.x, tid = threadIdx.x;
    if (blk < 27) {
        const float* src = fcw + (size_t)blk * 64 * 128;
        u16* dst = Wt + (size_t)blk * 128 * 64;
        for (int e = tid; e < 8192; e += 256) {
            int c = e >> 7, f = e & 127;
            dst[f * 64 + c] = f2b(src[c * 128 + f]);
        }
    } else {
        for (int e = tid; e < 16384; e += 256) {
            int o = e >> 7, k = e & 127;
            float v = (o < 64) ? cwl[(o * 64 + (k & 63)) * 2 + (k >> 6)]
                               : cwr[((o - 64) * 64 + (k & 63)) * 2 + (k >> 6)];
            Wc[o * 128 + k] = f2b(v);
        }
    }
}

// ---------------------------------------------------------------------------
// gated dilated conv as GEMM (unchanged)
// ---------------------------------------------------------------------------
__global__ __launch_bounds__(256) void dconv_gemm(
    const u16* __restrict__ Xn, const u16* __restrict__ Wc,
    const float* __restrict__ cbl, const float* __restrict__ cbr,
    float* __restrict__ out) {
    const int n0 = blockIdx.x * 128, t = blockIdx.y, b = blockIdx.z;
    const int tid = threadIdx.x, lane = tid & 63, wid = tid >> 6;
    __shared__ u16 alds[2][128 * 32];
    const u16* base0 = Xn + (size_t)(b * 12 + t) * 1024 * 64;
    const u16* base3 = Xn + (size_t)(b * 12 + t + 3) * 1024 * 64;

    auto stage = [&](int buf, int kt) {
        int k0 = kt * 32;
#pragma unroll
        for (int q = 0; q < 2; q++) {
            int r = wid * 32 + q * 16 + (lane >> 2);
            int k = k0 + (lane & 3) * 8;
            const u16* gs = (k < 64) ? base0 + (size_t)(n0 + r) * 64 + k
                                     : base3 + (size_t)(n0 + r) * 64 + (k - 64);
            GLL(gs, &alds[buf][(wid * 32 + q * 16) * 32]);
        }
    };

    f32x4 acc[2][8] = {};
    stage(0, 0);
    __syncthreads();
    const int a_off = (wid * 32 + (lane & 15)) * 32 + (lane >> 4) * 8;
    for (int kt = 0; kt < 4; kt++) {
        int cur = kt & 1;
        if (kt < 3) stage(cur ^ 1, kt + 1);
        bf16x8 af[2];
#pragma unroll
        for (int m = 0; m < 2; m++) af[m] = *(const bf16x8*)&alds[cur][a_off + m * 16 * 32];
#pragma unroll
        for (int n = 0; n < 8; n++) {
            bf16x8 bq = *(const bf16x8*)&Wc[(n * 16 + (lane & 15)) * 128 + kt * 32 + (lane >> 4) * 8];
#pragma unroll
            for (int m = 0; m < 2; m++)
                acc[m][n] = __builtin_amdgcn_mfma_f32_16x16x32_bf16(af[m], bq, acc[m][n], 0, 0, 0);
        }
        __syncthreads();
    }
#pragma unroll
    for (int m = 0; m < 2; m++) {
#pragma unroll
        for (int n = 0; n < 4; n++) {
            int fp = n * 16 + (lane & 15);
            float b1 = cbl[fp], b2 = cbr[fp];
#pragma unroll
            for (int j = 0; j < 4; j++) {
                int row = wid * 32 + m * 16 + (lane >> 4) * 4 + j;
                float gl = acc[m][n][j] + b1;
                float gr = acc[m][n + 4][j] + b2;
                out[((size_t)(b * 9 + t) * 1024 + n0 + row) * 64 + fp] =
                    (1.0f / (1.0f + expf(-gl))) * tanhf(gr);
            }
        }
    }
}

// ---------------------------------------------------------------------------
// 8-phase 256x256 agg GEMM with FUSED GLU epilogue + XCD swizzle.
// Main loop: Y[(b,c)][v] = sum_w A[(b,c)][w] * adj[vbase+v][w]
// Epilogue:  P[(b,f)][v] = GLU(W^T Y + bias) directly (stride nout).
// STAGE: 0 -> A from XT (windowed); 1 -> A = P [z][2048][4096].
// Scheduling: per-phase sched_barrier(0x38F) pins only VMEM issue order
// (needed for the counted vmcnt gate); VALU/DS/MFMA schedule freely.
// ---------------------------------------------------------------------------
#define PIN() __builtin_amdgcn_sched_barrier(0x38F)
#define BAR() __builtin_amdgcn_s_barrier()
#define GATE() asm volatile("s_waitcnt vmcnt(4)" ::: "memory")
#define GATE0() asm volatile("s_waitcnt vmcnt(0)" ::: "memory")

template <int STAGE>
__global__ __launch_bounds__(512, 2) void agg_gemm8(
    const u16* __restrict__ A, const u16* __restrict__ Bt,
    const u16* __restrict__ Wt, const float* __restrict__ fcb,
    u16* __restrict__ P, int win0, int vbase, int nout, int ks) {
    const int tid = threadIdx.x, lane = tid & 63, wid = tid >> 6;
    const int wr = wid >> 2, wc = wid & 3;
    // XCD-aware bijective swizzle (nwg = gx*gy*gz, gx*gy divisible by 8)
    const u32 gx = gridDim.x, gy = gridDim.y;
    u32 lin = blockIdx.x + gx * (blockIdx.y + gy * blockIdx.z);
    u32 qq = (gx * gy * gridDim.z) >> 3;
    u32 swz = (lin & 7) * qq + (lin >> 3);
    const int bx = swz % gx;
    const int by = (swz / gx) % gy;
    const int z  = swz / (gx * gy);
    const int rowBase = by * 256, colBase = bx * 256;
    const int win = win0 + z;
    __shared__ u16 lds[2][2][2][128 * 64];  // 128 KiB
    __shared__ float biasSm[128];
    if (tid < 128) biasSm[tid] = fcb[(win * 3 + ks) * 128 + tid];
    const u16* Az = (STAGE == 0) ? A : (A + (size_t)z * 2048 * 4096);

    const int srow = lane >> 3;
    const int skb  = 8 * ((lane & 7) ^ srow);

    auto stageA = [&](int buf, int half, int s, int kt) {
        int r0 = s * 64 + wid * 8;
        int row_g = rowBase + half * 128 + r0 + srow;
        const u16* src;
        if (STAGE == 0) {
            int k = kt * 64 + skb;
            src = Az + (size_t)row_g * 12288 + (size_t)(win + (k >> 10)) * 1024 + (k & 1023);
        } else {
            src = Az + (size_t)row_g * 4096 + kt * 64 + skb;
        }
        GLL(src, &lds[buf][0][half][r0 * 64]);
    };
    auto stageB = [&](int buf, int half, int s, int kt) {
        int r0 = s * 64 + wid * 8;
        int col_g = vbase + colBase + half * 128 + r0 + srow;
        GLL(Bt + (size_t)col_g * 4096 + kt * 64 + skb, &lds[buf][1][half][r0 * 64]);
    };
#define STH_A(buf, half, kt) do { stageA(buf, half, 0, kt); stageA(buf, half, 1, kt); } while (0)
#define STH_B(buf, half, kt) do { stageB(buf, half, 0, kt); stageB(buf, half, 1, kt); } while (0)

    f32x4 acc[8][4] = {};
    bf16x8 aF[4][2], bF[4][2];

#define READ_A(buf, mb)                                                       \
    _Pragma("unroll") for (int mm = 0; mm < 4; mm++)                          \
    _Pragma("unroll") for (int kk = 0; kk < 2; kk++) {                        \
        int r = ((mb) + mm) * 16 + (lane & 15);                               \
        int hw = (kk * 32 + (lane >> 4) * 8) ^ ((r & 7) << 3);                \
        aF[mm][kk] = *(const bf16x8*)&lds[buf][0][wr][r * 64 + hw];           \
    }
#define READ_B(buf, nb)                                                       \
    _Pragma("unroll") for (int nn = 0; nn < 2; nn++)                          \
    _Pragma("unroll") for (int kk = 0; kk < 2; kk++) {                        \
        int r = (wc & 1) * 64 + ((nb) + nn) * 16 + (lane & 15);               \
        int hw = (kk * 32 + (lane >> 4) * 8) ^ ((r & 7) << 3);                \
        bF[(nb) + nn][kk] = *(const bf16x8*)&lds[buf][1][wc >> 1][r * 64 + hw]; \
    }
#define MFMA8(mb, nb)                                                         \
    __builtin_amdgcn_s_setprio(1);                                            \
    _Pragma("unroll") for (int mm = 0; mm < 4; mm++)                          \
    _Pragma("unroll") for (int nn = 0; nn < 2; nn++)                          \
    _Pragma("unroll") for (int kk = 0; kk < 2; kk++)                          \
        acc[(mb) + mm][(nb) + nn] = __builtin_amdgcn_mfma_f32_16x16x32_bf16(  \
            aF[mm][kk], bF[(nb) + nn][kk], acc[(mb) + mm][(nb) + nn], 0, 0, 0); \
    __builtin_amdgcn_s_setprio(0);

    // prologue: tile0 -> buf0; tile1 -> buf1 (B0,A0). PIN keeps issue order
    // so vmcnt(4) leaves exactly tile1's 4 loads in flight.
    STH_B(0, 0, 0); STH_A(0, 0, 0); STH_B(0, 1, 0); STH_A(0, 1, 0);
    PIN();
    STH_B(1, 0, 1); STH_A(1, 0, 1);
    GATE();
    BAR();

    for (int i = 0; i < 31; i++) {
        int t1 = 2 * i + 1, t2 = 2 * i + 2, t3 = 2 * i + 3;
        // ---- K-tile 2i in buf0 ----
        READ_A(0, 0); READ_B(0, 0);
        STH_B(1, 1, t1);
        PIN(); BAR(); MFMA8(0, 0); BAR();

        READ_B(0, 2);
        STH_A(1, 1, t1);
        PIN(); BAR(); MFMA8(0, 2); BAR();

        READ_A(0, 4);
        STH_B(0, 0, t2);
        PIN(); BAR(); MFMA8(4, 0); BAR();

        STH_A(0, 0, t2);
        PIN(); BAR(); MFMA8(4, 2); GATE(); BAR();   // tile 2i+1 fully landed

        // ---- K-tile 2i+1 in buf1 ----
        READ_A(1, 0); READ_B(1, 0);
        STH_B(0, 1, t2);
        PIN(); BAR(); MFMA8(0, 0); BAR();

        READ_B(1, 2);
        STH_A(0, 1, t2);
        PIN(); BAR(); MFMA8(0, 2); BAR();

        READ_A(1, 4);
        STH_B(1, 0, t3);
        PIN(); BAR(); MFMA8(4, 0); BAR();

        STH_A(1, 0, t3);
        PIN(); BAR(); MFMA8(4, 2); GATE(); BAR();   // tile 2i+2 fully landed
    }

    // ---- peeled tail: K-tile 62 (buf0), finish staging 63; K-tile 63 (buf1)
    READ_A(0, 0); READ_B(0, 0);
    STH_B(1, 1, 63);
    PIN(); BAR(); MFMA8(0, 0); BAR();

    READ_B(0, 2);
    STH_A(1, 1, 63);
    PIN(); BAR(); MFMA8(0, 2); BAR();

    READ_A(0, 4);
    BAR(); MFMA8(4, 0); BAR();

    MFMA8(4, 2); GATE0(); BAR();           // all loads drained

    READ_A(1, 0); READ_B(1, 0);
    BAR(); MFMA8(0, 0); BAR();
    READ_B(1, 2);
    BAR(); MFMA8(0, 2); BAR();
    READ_A(1, 4);
    BAR(); MFMA8(4, 0); BAR();
    MFMA8(4, 2);

    // ================= fused GLU epilogue =================
    __syncthreads();  // all MFMA/ds reads done; LDS reusable
    u16* YT = &lds[0][0][0][0];  // [4 batch][256 v][64 c] bf16, 16B-granule swizzled

    // stage 1: acc -> YT
#pragma unroll
    for (int m = 0; m < 8; m++) {
        int bi = wr * 2 + (m >> 2);
        int c0 = (m & 3) * 16 + (lane >> 4) * 4;
#pragma unroll
        for (int n = 0; n < 4; n++) {
            int v = wc * 64 + n * 16 + (lane & 15);
            ushort4 pk;
            pk.x = f2b(acc[m][n][0]); pk.y = f2b(acc[m][n][1]);
            pk.z = f2b(acc[m][n][2]); pk.w = f2b(acc[m][n][3]);
            int addr = bi * 16384 + v * 64 + (((c0 >> 3) ^ (v & 7)) << 3) + (c0 & 7);
            *(ushort4*)&YT[addr] = pk;
        }
    }
    __syncthreads();

    // stage 2: P[f][v] = GLU(W^T Y + bias)
    const int bi2 = wid >> 1, h = wid & 1;
    const u16* Wl = Wt + (size_t)(win * 3 + ks) * 8192;
    u16* Pz = P + (size_t)z * 2048 * nout;
#pragma unroll
    for (int vq = 0; vq < 2; vq++) {
        f32x4 acc2[8][4] = {};
        bf16x8 bq2[4][2];
#pragma unroll
        for (int nt = 0; nt < 4; nt++) {
            int v = h * 128 + vq * 64 + nt * 16 + (lane & 15);
#pragma unroll
            for (int kk = 0; kk < 2; kk++) {
                int g = kk * 4 + (lane >> 4);
                bq2[nt][kk] = *(const bf16x8*)&YT[bi2 * 16384 + v * 64 + ((g ^ (v & 7)) << 3)];
            }
        }
#pragma unroll
        for (int fi = 0; fi < 8; fi++) {
            bf16x8 aw[2];
#pragma unroll
            for (int kk = 0; kk < 2; kk++)
                aw[kk] = *(const bf16x8*)&Wl[(fi * 16 + (lane & 15)) * 64 + kk * 32 + (lane >> 4) * 8];
#pragma unroll
            for (int nt = 0; nt < 4; nt++)
#pragma unroll
                for (int kk = 0; kk < 2; kk++)
                    acc2[fi][nt] = __builtin_amdgcn_mfma_f32_16x16x32_bf16(
                        aw[kk], bq2[nt][kk], acc2[fi][nt], 0, 0, 0);
        }
#pragma unroll
        for (int fi = 0; fi < 4; fi++) {
#pragma unroll
            for (int j = 0; j < 4; j++) {
                int f = fi * 16 + (lane >> 4) * 4 + j;
                float b1 = biasSm[f], b2v = biasSm[f + 64];
#pragma unroll
                for (int nt = 0; nt < 4; nt++) {
                    float g1 = acc2[fi][nt][j] + b1;
                    float g2 = acc2[fi + 4][nt][j] + b2v;
                    float val = g1 / (1.0f + expf(-g2));
                    int row = rowBase + bi2 * 64 + f;
                    int col = colBase + h * 128 + vq * 64 + nt * 16 + (lane & 15);
                    Pz[(size_t)row * nout + col] = f2b(val);
                }
            }
        }
    }
#undef READ_A
#undef READ_B
#undef MFMA8
#undef STH_A
#undef STH_B
}

// ---------------------------------------------------------------------------
// final: out[b,win,n,f] += max(P1mid, P2mid, P3)
// ---------------------------------------------------------------------------
__global__ void final_add(const u16* __restrict__ P1, const u16* __restrict__ P2,
                          const u16* __restrict__ P3, float* __restrict__ out, int win0) {
    const int n0 = blockIdx.x * 64, b = blockIdx.y, z = blockIdx.z;
    const int win = win0 + z;
    const int tid = threadIdx.x;
    __shared__ float tl[64][65];
    {
        int f = tid >> 2, q = tid & 3;
        size_t o12 = ((size_t)z * 2048 + b * 64 + f) * 4096 + 1024 + n0 + q * 16;
        size_t o3  = ((size_t)z * 2048 + b * 64 + f) * 1024 + n0 + q * 16;
#pragma unroll
        for (int i = 0; i < 16; i += 4) {
            uint2 a  = *(const uint2*)&P1[o12 + i];
            uint2 c2 = *(const uint2*)&P2[o12 + i];
            uint2 d  = *(const uint2*)&P3[o3 + i];
            u32 av[4] = {a.x & 0xffffu, a.x >> 16, a.y & 0xffffu, a.y >> 16};
            u32 bv[4] = {c2.x & 0xffffu, c2.x >> 16, c2.y & 0xffffu, c2.y >> 16};
            u32 dv[4] = {d.x & 0xffffu, d.x >> 16, d.y & 0xffffu, d.y >> 16};
#pragma unroll
            for (int jj = 0; jj < 4; jj++)
                tl[q * 16 + i + jj][f] = fmaxf(fmaxf(b2f(av[jj]), b2f(bv[jj])), b2f(dv[jj]));
        }
    }
    __syncthreads();
    {
        int n = tid >> 2, q = tid & 3;
        size_t oo = ((size_t)(b * 9 + win) * 1024 + n0 + n) * 64 + q * 16;
#pragma unroll
        for (int i = 0; i < 16; i += 4) {
            float4 cur = *(const float4*)&out[oo + i];
            cur.x += tl[n][q * 16 + i + 0];
            cur.y += tl[n][q * 16 + i + 1];
            cur.z += tl[n][q * 16 + i + 2];
            cur.w += tl[n][q * 16 + i + 3];
            *(float4*)&out[oo + i] = cur;
        }
    }
}

// ---------------------------------------------------------------------------
extern "C" void kernel_launch(void* const* d_in, const int* in_sizes, int n_in,
                              void* d_out, int out_size, void* d_ws, size_t ws_size,
                              hipStream_t stream) {
    const float* data = (const float*)d_in[0];
    const float* adj  = (const float*)d_in[1];
    const float* temb = (const float*)d_in[2];
    const float* semb = (const float*)d_in[3];
    const float* cwl  = (const float*)d_in[4];
    const float* cbl  = (const float*)d_in[5];
    const float* cwr  = (const float*)d_in[6];
    const float* cbr  = (const float*)d_in[7];
    const float* fcw  = (const float*)d_in[8];
    const float* fcb  = (const float*)d_in[9];
    float* out = (float*)d_out;

    char* p = (char*)d_ws;
    auto alloc = [&](size_t bytes) -> char* {
        char* r = p;
        p += (bytes + 255) & ~(size_t)255;
        return r;
    };
    const size_t SZ_XT  = 2048UL * 12288 * 2;
    const size_t SZ_XN  = 32UL * 12 * 1024 * 64 * 2;
    const size_t SZ_ADJ = 4096UL * 4096 * 2;
    const size_t SZ_WT  = 27UL * 128 * 64 * 2;
    const size_t SZ_WC  = 128UL * 128 * 2;
    const size_t SZ_P12 = 2048UL * 4096 * 2;  // 16 MiB
    const size_t SZ_P3  = 2048UL * 1024 * 2;  //  4 MiB
    u16* XT   = (u16*)alloc(SZ_XT);
    u16* adjb = (u16*)alloc(SZ_ADJ);
    u16* Wt   = (u16*)alloc(SZ_WT);
    u16* Wc   = (u16*)alloc(SZ_WC);

    char* winBase = p;
    size_t avail = ws_size - (size_t)(winBase - (char*)d_ws);
    const size_t perwin = 2 * SZ_P12 + SZ_P3 + 3 * 256;
    int cap = (int)(avail / perwin);
    if (cap > 9) cap = 9;
    if (cap < 1) cap = 1;
    u16* P1 = (u16*)alloc((size_t)cap * SZ_P12);
    u16* P2 = (u16*)alloc((size_t)cap * SZ_P12);
    u16* P3 = (u16*)alloc((size_t)cap * SZ_P3);
    // Xn aliases the window-buffer region (dead before first P write)
    u16* Xn = ((size_t)cap * perwin >= SZ_XN + 256) ? (u16*)winBase : (u16*)alloc(SZ_XN);

    cvt_f32_bf16<<<4096, 256, 0, stream>>>(adj, adjb, 4096 * 4096);
    prep_x<<<dim3(16, 12, 32), 256, 0, stream>>>(data, temb, semb, Xn, XT);
    prep_w<<<28, 256, 0, stream>>>(fcw, cwl, cwr, Wt, Wc);
    dconv_gemm<<<dim3(8, 9, 32), 256, 0, stream>>>(Xn, Wc, cbl, cbr, out);

    // balanced window groups (avoid lopsided {8,1} splits)
    int ngroups = (9 + cap - 1) / cap;
    int gbase = 9 / ngroups, grem = 9 % ngroups;
    int w0 = 0;
    for (int g = 0; g < ngroups; g++) {
        int cw = gbase + (g < grem ? 1 : 0);
        agg_gemm8<0><<<dim3(16, 8, cw), 512, 0, stream>>>(XT, adjb, Wt, fcb, P1, w0, 0, 4096, 0);
        agg_gemm8<1><<<dim3(16, 8, cw), 512, 0, stream>>>(P1, adjb, Wt, fcb, P2, w0, 0, 4096, 1);
        agg_gemm8<1><<<dim3(4, 8, cw), 512, 0, stream>>>(P2, adjb, Wt, fcb, P3, w0, 1024, 1024, 2);
        final_add<<<dim3(16, 32, cw), 256, 0, stream>>>(P1, P2, P3, out, w0);
        w0 += cw;
    }
}

// Round 5
// 1690.729 us; speedup vs baseline: 1.1630x; 1.0897x over previous
//
#include <hip/hip_runtime.h>
#include <math.h>

typedef unsigned short u16;
typedef unsigned int   u32;
typedef __attribute__((ext_vector_type(8))) short bf16x8;
typedef __attribute__((ext_vector_type(4))) float f32x4;

typedef const void __attribute__((address_space(1))) gv1_t;
typedef void       __attribute__((address_space(3))) lv3_t;
#define GLL(g, l) __builtin_amdgcn_global_load_lds((gv1_t*)(g), (lv3_t*)(l), 16, 0, 0)

__device__ __forceinline__ u16 f2b(float x) {
    union { float f; u32 u; } v; v.f = x;
    u32 r = v.u + 0x7FFFu + ((v.u >> 16) & 1u);
    return (u16)(r >> 16);
}
__device__ __forceinline__ float b2f(u32 x) {
    union { u32 u; float f; } v; v.u = x << 16;
    return v.f;
}
__device__ __forceinline__ float fast_sigmoid(float x) {
    return __builtin_amdgcn_rcpf(1.0f + __builtin_amdgcn_exp2f(-x * 1.44269504f));
}
__device__ __forceinline__ float fast_tanh(float x) {
    return 2.0f * __builtin_amdgcn_rcpf(1.0f + __builtin_amdgcn_exp2f(-x * 2.88539008f)) - 1.0f;
}

// ---------------------------------------------------------------------------
// prep: f32 -> bf16 convert (adj)
// ---------------------------------------------------------------------------
__global__ void cvt_f32_bf16(const float* __restrict__ a, u16* __restrict__ o, int n) {
    for (int i = (blockIdx.x * 256 + threadIdx.x) * 4; i < n; i += gridDim.x * 256 * 4) {
        float4 v = *(const float4*)&a[i];
        uint2 pk;
        pk.x = (u32)f2b(v.x) | ((u32)f2b(v.y) << 16);
        pk.y = (u32)f2b(v.z) | ((u32)f2b(v.w) << 16);
        *(uint2*)&o[i] = pk;
    }
}

// ---------------------------------------------------------------------------
// prep: x = data + temb + semb; write Xn [b][t][n][c] bf16 and XT [(b,c)][t*1024+n]
// ---------------------------------------------------------------------------
__global__ void prep_x(const float* __restrict__ data, const float* __restrict__ temb,
                       const float* __restrict__ semb, u16* __restrict__ Xn, u16* __restrict__ XT) {
    const int n0 = blockIdx.x * 64, t = blockIdx.y, b = blockIdx.z;
    const int tid = threadIdx.x;
    __shared__ u16 lt[64][66];
#pragma unroll
    for (int p = 0; p < 4; p++) {
        int n = p * 16 + (tid >> 4);
        int c = (tid & 15) * 4;
        size_t gi = ((size_t)(b * 12 + t) * 1024 + n0 + n) * 64 + c;
        float4 v  = *(const float4*)&data[gi];
        float4 tv = *(const float4*)&temb[t * 64 + c];
        float4 sv = *(const float4*)&semb[(n0 + n) * 64 + c];
        u16 u0 = f2b(v.x + tv.x + sv.x);
        u16 u1 = f2b(v.y + tv.y + sv.y);
        u16 u2 = f2b(v.z + tv.z + sv.z);
        u16 u3 = f2b(v.w + tv.w + sv.w);
        uint2 pk; pk.x = (u32)u0 | ((u32)u1 << 16); pk.y = (u32)u2 | ((u32)u3 << 16);
        *(uint2*)&Xn[gi] = pk;
        lt[n][c + 0] = u0; lt[n][c + 1] = u1; lt[n][c + 2] = u2; lt[n][c + 3] = u3;
    }
    __syncthreads();
    const int c = tid >> 2, q = tid & 3;
    u16 u[16];
#pragma unroll
    for (int i = 0; i < 16; i++) u[i] = lt[q * 16 + i][c];
    size_t xo = ((size_t)(b * 64 + c)) * 12288 + (size_t)t * 1024 + n0 + q * 16;
    uint4 p0, p1;
    p0.x = (u32)u[0] | ((u32)u[1] << 16);  p0.y = (u32)u[2] | ((u32)u[3] << 16);
    p0.z = (u32)u[4] | ((u32)u[5] << 16);  p0.w = (u32)u[6] | ((u32)u[7] << 16);
    p1.x = (u32)u[8] | ((u32)u[9] << 16);  p1.y = (u32)u[10] | ((u32)u[11] << 16);
    p1.z = (u32)u[12] | ((u32)u[13] << 16); p1.w = (u32)u[14] | ((u32)u[15] << 16);
    *(uint4*)&XT[xo] = p0;
    *(uint4*)&XT[xo + 8] = p1;
}

// ---------------------------------------------------------------------------
// prep: fc_w [27][64][128] -> Wt [27][128][64] bf16 ; conv weights -> Wc bf16
// ---------------------------------------------------------------------------
__global__ void prep_w(const float* __restrict__ fcw, const float* __restrict__ cwl,
                       const float* __restrict__ cwr, u16* __restrict__ Wt, u16* __restrict__ Wc) {
    const int blk = blockIdx.x, tid = threadIdx.x;
    if (blk < 27) {
        const float* src = fcw + (size_t)blk * 64 * 128;
        u16* dst = Wt + (size_t)blk * 128 * 64;
        for (int e = tid; e < 8192; e += 256) {
            int c = e >> 7, f = e & 127;
            dst[f * 64 + c] = f2b(src[c * 128 + f]);
        }
    } else {
        for (int e = tid; e < 16384; e += 256) {
            int o = e >> 7, k = e & 127;
            float v = (o < 64) ? cwl[(o * 64 + (k & 63)) * 2 + (k >> 6)]
                               : cwr[((o - 64) * 64 + (k & 63)) * 2 + (k >> 6)];
            Wc[o * 128 + k] = f2b(v);
        }
    }
}

// ---------------------------------------------------------------------------
// gated dilated conv as GEMM
// ---------------------------------------------------------------------------
__global__ __launch_bounds__(256) void dconv_gemm(
    const u16* __restrict__ Xn, const u16* __restrict__ Wc,
    const float* __restrict__ cbl, const float* __restrict__ cbr,
    float* __restrict__ out) {
    const int n0 = blockIdx.x * 128, t = blockIdx.y, b = blockIdx.z;
    const int tid = threadIdx.x, lane = tid & 63, wid = tid >> 6;
    __shared__ u16 alds[2][128 * 32];
    const u16* base0 = Xn + (size_t)(b * 12 + t) * 1024 * 64;
    const u16* base3 = Xn + (size_t)(b * 12 + t + 3) * 1024 * 64;

    auto stage = [&](int buf, int kt) {
        int k0 = kt * 32;
#pragma unroll
        for (int q = 0; q < 2; q++) {
            int r = wid * 32 + q * 16 + (lane >> 2);
            int k = k0 + (lane & 3) * 8;
            const u16* gs = (k < 64) ? base0 + (size_t)(n0 + r) * 64 + k
                                     : base3 + (size_t)(n0 + r) * 64 + (k - 64);
            GLL(gs, &alds[buf][(wid * 32 + q * 16) * 32]);
        }
    };

    f32x4 acc[2][8] = {};
    stage(0, 0);
    __syncthreads();
    const int a_off = (wid * 32 + (lane & 15)) * 32 + (lane >> 4) * 8;
    for (int kt = 0; kt < 4; kt++) {
        int cur = kt & 1;
        if (kt < 3) stage(cur ^ 1, kt + 1);
        bf16x8 af[2];
#pragma unroll
        for (int m = 0; m < 2; m++) af[m] = *(const bf16x8*)&alds[cur][a_off + m * 16 * 32];
#pragma unroll
        for (int n = 0; n < 8; n++) {
            bf16x8 bq = *(const bf16x8*)&Wc[(n * 16 + (lane & 15)) * 128 + kt * 32 + (lane >> 4) * 8];
#pragma unroll
            for (int m = 0; m < 2; m++)
                acc[m][n] = __builtin_amdgcn_mfma_f32_16x16x32_bf16(af[m], bq, acc[m][n], 0, 0, 0);
        }
        __syncthreads();
    }
#pragma unroll
    for (int m = 0; m < 2; m++) {
#pragma unroll
        for (int n = 0; n < 4; n++) {
            int fp = n * 16 + (lane & 15);
            float b1 = cbl[fp], b2 = cbr[fp];
#pragma unroll
            for (int j = 0; j < 4; j++) {
                int row = wid * 32 + m * 16 + (lane >> 4) * 4 + j;
                float gl = acc[m][n][j] + b1;
                float gr = acc[m][n + 4][j] + b2;
                out[((size_t)(b * 9 + t) * 1024 + n0 + row) * 64 + fp] =
                    fast_sigmoid(gl) * fast_tanh(gr);
            }
        }
    }
}

// ---------------------------------------------------------------------------
// 8-phase 256x256 agg GEMM with FUSED GLU epilogue.
// Main loop: Y[(b,c)][v] = sum_w A[(b,c)][w] * adj[vbase+v][w]
// Epilogue:  P[(b,f)][v] = GLU(W^T Y + bias) directly (stride nout).
// Schedule: round-2-proven full sched_barrier(0) pinning; phases split along
// K (reads balanced 8/8/8/0); counted vmcnt(4) gates at phase 4/8.
// ---------------------------------------------------------------------------
#define SB() do { __builtin_amdgcn_sched_barrier(0); __builtin_amdgcn_s_barrier(); __builtin_amdgcn_sched_barrier(0); } while (0)
#define GATE() asm volatile("s_waitcnt vmcnt(4)" ::: "memory")
#define GATE0() asm volatile("s_waitcnt vmcnt(0)" ::: "memory")

template <int STAGE>
__global__ __launch_bounds__(512, 2) void agg_gemm8(
    const u16* __restrict__ A, const u16* __restrict__ Bt,
    const u16* __restrict__ Wt, const float* __restrict__ fcb,
    u16* __restrict__ P, int win0, int vbase, int nout, int ks) {
    const int tid = threadIdx.x, lane = tid & 63, wid = tid >> 6;
    const int wr = wid >> 2, wc = wid & 3;
    const int bx = blockIdx.x, by = blockIdx.y, z = blockIdx.z;
    const int rowBase = by * 256, colBase = bx * 256;
    const int win = win0 + z;
    __shared__ u16 lds[2][2][2][128 * 64];  // 128 KiB
    __shared__ float biasSm[128];
    biasSm[tid & 127] = fcb[(win * 3 + ks) * 128 + (tid & 127)];
    const u16* Az = (STAGE == 0) ? A : (A + (size_t)z * 2048 * 4096);

    const int srow = lane >> 3;
    const int skb  = 8 * ((lane & 7) ^ srow);

    auto stageA = [&](int buf, int half, int s, int kt) {
        int r0 = s * 64 + wid * 8;
        int row_g = rowBase + half * 128 + r0 + srow;
        const u16* src;
        if (STAGE == 0) {
            int k = kt * 64 + skb;
            src = Az + (size_t)row_g * 12288 + (size_t)(win + (k >> 10)) * 1024 + (k & 1023);
        } else {
            src = Az + (size_t)row_g * 4096 + kt * 64 + skb;
        }
        GLL(src, &lds[buf][0][half][r0 * 64]);
    };
    auto stageB = [&](int buf, int half, int s, int kt) {
        int r0 = s * 64 + wid * 8;
        int col_g = vbase + colBase + half * 128 + r0 + srow;
        GLL(Bt + (size_t)col_g * 4096 + kt * 64 + skb, &lds[buf][1][half][r0 * 64]);
    };
#define STH_A(buf, half, kt) do { stageA(buf, half, 0, kt); stageA(buf, half, 1, kt); } while (0)
#define STH_B(buf, half, kt) do { stageB(buf, half, 0, kt); stageB(buf, half, 1, kt); } while (0)

    f32x4 acc[8][4] = {};
    bf16x8 aF[4][2], bF[4][2];

#define READ_AK(buf, mb, kk)                                                  \
    _Pragma("unroll") for (int mm = 0; mm < 4; mm++) {                        \
        int r = ((mb) + mm) * 16 + (lane & 15);                               \
        int hw = ((kk) * 32 + (lane >> 4) * 8) ^ ((r & 7) << 3);              \
        aF[mm][kk] = *(const bf16x8*)&lds[buf][0][wr][r * 64 + hw];           \
    }
#define READ_BK(buf, kk)                                                      \
    _Pragma("unroll") for (int nn = 0; nn < 4; nn++) {                        \
        int r = (wc & 1) * 64 + nn * 16 + (lane & 15);                        \
        int hw = ((kk) * 32 + (lane >> 4) * 8) ^ ((r & 7) << 3);              \
        bF[nn][kk] = *(const bf16x8*)&lds[buf][1][wc >> 1][r * 64 + hw];      \
    }
#define MFMA16(mb, kk)                                                        \
    __builtin_amdgcn_s_setprio(1);                                            \
    _Pragma("unroll") for (int mm = 0; mm < 4; mm++)                          \
    _Pragma("unroll") for (int nn = 0; nn < 4; nn++)                          \
        acc[(mb) + mm][nn] = __builtin_amdgcn_mfma_f32_16x16x32_bf16(         \
            aF[mm][kk], bF[nn][kk], acc[(mb) + mm][nn], 0, 0, 0);             \
    __builtin_amdgcn_s_setprio(0);

    // prologue: tile0 -> buf0; tile1 -> buf1 (B half0, A half0)
    STH_B(0, 0, 0); STH_A(0, 0, 0); STH_B(0, 1, 0); STH_A(0, 1, 0);
    __builtin_amdgcn_sched_barrier(0);
    STH_B(1, 0, 1); STH_A(1, 0, 1);
    GATE();
    SB();

    for (int i = 0; i < 31; i++) {
        int t1 = 2 * i + 1, t2 = 2 * i + 2, t3 = 2 * i + 3;
        // ---- K-tile 2i in buf0 ----
        READ_AK(0, 0, 0); READ_BK(0, 0);
        STH_B(1, 1, t1);
        SB(); MFMA16(0, 0); SB();

        READ_AK(0, 0, 1); READ_BK(0, 1);
        STH_A(1, 1, t1);
        SB(); MFMA16(0, 1); SB();

        READ_AK(0, 4, 0); READ_AK(0, 4, 1);
        STH_B(0, 0, t2);
        SB(); MFMA16(4, 0); SB();

        STH_A(0, 0, t2);
        SB(); MFMA16(4, 1); GATE(); SB();   // tile 2i+1 fully landed

        // ---- K-tile 2i+1 in buf1 ----
        READ_AK(1, 0, 0); READ_BK(1, 0);
        STH_B(0, 1, t2);
        SB(); MFMA16(0, 0); SB();

        READ_AK(1, 0, 1); READ_BK(1, 1);
        STH_A(0, 1, t2);
        SB(); MFMA16(0, 1); SB();

        READ_AK(1, 4, 0); READ_AK(1, 4, 1);
        STH_B(1, 0, t3);
        SB(); MFMA16(4, 0); SB();

        STH_A(1, 0, t3);
        SB(); MFMA16(4, 1); GATE(); SB();   // tile 2i+2 fully landed
    }

    // ---- peeled tail: K-tile 62 (buf0, finish staging 63); K-tile 63 (buf1)
    READ_AK(0, 0, 0); READ_BK(0, 0);
    STH_B(1, 1, 63);
    SB(); MFMA16(0, 0); SB();

    READ_AK(0, 0, 1); READ_BK(0, 1);
    STH_A(1, 1, 63);
    SB(); MFMA16(0, 1); SB();

    READ_AK(0, 4, 0); READ_AK(0, 4, 1);
    SB(); MFMA16(4, 0); SB();

    MFMA16(4, 1); GATE0(); SB();           // all loads drained

    READ_AK(1, 0, 0); READ_BK(1, 0);
    SB(); MFMA16(0, 0); SB();
    READ_AK(1, 0, 1); READ_BK(1, 1);
    SB(); MFMA16(0, 1); SB();
    READ_AK(1, 4, 0); READ_AK(1, 4, 1);
    SB(); MFMA16(4, 0); SB();
    MFMA16(4, 1);

    // ================= fused GLU epilogue =================
    __syncthreads();  // all MFMA/ds reads done; LDS reusable
    u16* YT = &lds[0][0][0][0];  // [4 batch][256 v][64 c] bf16, 16B-granule swizzled

    // stage 1: acc -> YT
#pragma unroll
    for (int m = 0; m < 8; m++) {
        int bi = wr * 2 + (m >> 2);
        int c0 = (m & 3) * 16 + (lane >> 4) * 4;
#pragma unroll
        for (int n = 0; n < 4; n++) {
            int v = wc * 64 + n * 16 + (lane & 15);
            ushort4 pk;
            pk.x = f2b(acc[m][n][0]); pk.y = f2b(acc[m][n][1]);
            pk.z = f2b(acc[m][n][2]); pk.w = f2b(acc[m][n][3]);
            int addr = bi * 16384 + v * 64 + (((c0 >> 3) ^ (v & 7)) << 3) + (c0 & 7);
            *(ushort4*)&YT[addr] = pk;
        }
    }
    __syncthreads();

    // stage 2: P[f][v] = GLU(W^T Y + bias); weights hoisted out of vq loop
    const int bi2 = wid >> 1, h = wid & 1;
    const u16* Wl = Wt + (size_t)(win * 3 + ks) * 8192;
    u16* Pz = P + (size_t)z * 2048 * nout;
    bf16x8 aw[8][2];
#pragma unroll
    for (int fi = 0; fi < 8; fi++)
#pragma unroll
        for (int kk = 0; kk < 2; kk++)
            aw[fi][kk] = *(const bf16x8*)&Wl[(fi * 16 + (lane & 15)) * 64 + kk * 32 + (lane >> 4) * 8];
#pragma unroll
    for (int vq = 0; vq < 2; vq++) {
        f32x4 acc2[8][4] = {};
        bf16x8 bq2[4][2];
#pragma unroll
        for (int nt = 0; nt < 4; nt++) {
            int v = h * 128 + vq * 64 + nt * 16 + (lane & 15);
#pragma unroll
            for (int kk = 0; kk < 2; kk++) {
                int g = kk * 4 + (lane >> 4);
                bq2[nt][kk] = *(const bf16x8*)&YT[bi2 * 16384 + v * 64 + ((g ^ (v & 7)) << 3)];
            }
        }
#pragma unroll
        for (int fi = 0; fi < 8; fi++)
#pragma unroll
            for (int nt = 0; nt < 4; nt++)
#pragma unroll
                for (int kk = 0; kk < 2; kk++)
                    acc2[fi][nt] = __builtin_amdgcn_mfma_f32_16x16x32_bf16(
                        aw[fi][kk], bq2[nt][kk], acc2[fi][nt], 0, 0, 0);
#pragma unroll
        for (int fi = 0; fi < 4; fi++) {
#pragma unroll
            for (int j = 0; j < 4; j++) {
                int f = fi * 16 + (lane >> 4) * 4 + j;
                float b1 = biasSm[f], b2v = biasSm[f + 64];
#pragma unroll
                for (int nt = 0; nt < 4; nt++) {
                    float g1 = acc2[fi][nt][j] + b1;
                    float g2 = acc2[fi + 4][nt][j] + b2v;
                    float val = g1 * fast_sigmoid(g2);
                    int row = rowBase + bi2 * 64 + f;
                    int col = colBase + h * 128 + vq * 64 + nt * 16 + (lane & 15);
                    Pz[(size_t)row * nout + col] = f2b(val);
                }
            }
        }
    }
#undef READ_AK
#undef READ_BK
#undef MFMA16
#undef STH_A
#undef STH_B
}

// ---------------------------------------------------------------------------
// final: out[b,win,n,f] += max(P1mid, P2mid, P3)
// ---------------------------------------------------------------------------
__global__ void final_add(const u16* __restrict__ P1, const u16* __restrict__ P2,
                          const u16* __restrict__ P3, float* __restrict__ out, int win0) {
    const int n0 = blockIdx.x * 64, b = blockIdx.y, z = blockIdx.z;
    const int win = win0 + z;
    const int tid = threadIdx.x;
    __shared__ float tl[64][65];
    {
        int f = tid >> 2, q = tid & 3;
        size_t o12 = ((size_t)z * 2048 + b * 64 + f) * 4096 + 1024 + n0 + q * 16;
        size_t o3  = ((size_t)z * 2048 + b * 64 + f) * 1024 + n0 + q * 16;
#pragma unroll
        for (int i = 0; i < 16; i += 4) {
            uint2 a  = *(const uint2*)&P1[o12 + i];
            uint2 c2 = *(const uint2*)&P2[o12 + i];
            uint2 d  = *(const uint2*)&P3[o3 + i];
            u32 av[4] = {a.x & 0xffffu, a.x >> 16, a.y & 0xffffu, a.y >> 16};
            u32 bv[4] = {c2.x & 0xffffu, c2.x >> 16, c2.y & 0xffffu, c2.y >> 16};
            u32 dv[4] = {d.x & 0xffffu, d.x >> 16, d.y & 0xffffu, d.y >> 16};
#pragma unroll
            for (int jj = 0; jj < 4; jj++)
                tl[q * 16 + i + jj][f] = fmaxf(fmaxf(b2f(av[jj]), b2f(bv[jj])), b2f(dv[jj]));
        }
    }
    __syncthreads();
    {
        int n = tid >> 2, q = tid & 3;
        size_t oo = ((size_t)(b * 9 + win) * 1024 + n0 + n) * 64 + q * 16;
#pragma unroll
        for (int i = 0; i < 16; i += 4) {
            float4 cur = *(const float4*)&out[oo + i];
            cur.x += tl[n][q * 16 + i + 0];
            cur.y += tl[n][q * 16 + i + 1];
            cur.z += tl[n][q * 16 + i + 2];
            cur.w += tl[n][q * 16 + i + 3];
            *(float4*)&out[oo + i] = cur;
        }
    }
}

// ---------------------------------------------------------------------------
extern "C" void kernel_launch(void* const* d_in, const int* in_sizes, int n_in,
                              void* d_out, int out_size, void* d_ws, size_t ws_size,
                              hipStream_t stream) {
    const float* data = (const float*)d_in[0];
    const float* adj  = (const float*)d_in[1];
    const float* temb = (const float*)d_in[2];
    const float* semb = (const float*)d_in[3];
    const float* cwl  = (const float*)d_in[4];
    const float* cbl  = (const float*)d_in[5];
    const float* cwr  = (const float*)d_in[6];
    const float* cbr  = (const float*)d_in[7];
    const float* fcw  = (const float*)d_in[8];
    const float* fcb  = (const float*)d_in[9];
    float* out = (float*)d_out;

    char* p = (char*)d_ws;
    auto alloc = [&](size_t bytes) -> char* {
        char* r = p;
        p += (bytes + 255) & ~(size_t)255;
        return r;
    };
    const size_t SZ_XT  = 2048UL * 12288 * 2;
    const size_t SZ_XN  = 32UL * 12 * 1024 * 64 * 2;
    const size_t SZ_ADJ = 4096UL * 4096 * 2;
    const size_t SZ_WT  = 27UL * 128 * 64 * 2;
    const size_t SZ_WC  = 128UL * 128 * 2;
    const size_t SZ_P12 = 2048UL * 4096 * 2;  // 16 MiB
    const size_t SZ_P3  = 2048UL * 1024 * 2;  //  4 MiB
    u16* XT   = (u16*)alloc(SZ_XT);
    u16* adjb = (u16*)alloc(SZ_ADJ);
    u16* Wt   = (u16*)alloc(SZ_WT);
    u16* Wc   = (u16*)alloc(SZ_WC);

    char* winBase = p;
    size_t avail = ws_size - (size_t)(winBase - (char*)d_ws);
    const size_t perwin = 2 * SZ_P12 + SZ_P3 + 3 * 256;
    int cap = (int)(avail / perwin);
    if (cap > 9) cap = 9;
    if (cap < 1) cap = 1;
    u16* P1 = (u16*)alloc((size_t)cap * SZ_P12);
    u16* P2 = (u16*)alloc((size_t)cap * SZ_P12);
    u16* P3 = (u16*)alloc((size_t)cap * SZ_P3);
    // Xn aliases the window-buffer region (dead before first P write)
    u16* Xn = ((size_t)cap * perwin >= SZ_XN + 256) ? (u16*)winBase : (u16*)alloc(SZ_XN);

    cvt_f32_bf16<<<4096, 256, 0, stream>>>(adj, adjb, 4096 * 4096);
    prep_x<<<dim3(16, 12, 32), 256, 0, stream>>>(data, temb, semb, Xn, XT);
    prep_w<<<28, 256, 0, stream>>>(fcw, cwl, cwr, Wt, Wc);
    dconv_gemm<<<dim3(8, 9, 32), 256, 0, stream>>>(Xn, Wc, cbl, cbr, out);

    // balanced window groups
    int ngroups = (9 + cap - 1) / cap;
    int gbase = 9 / ngroups, grem = 9 % ngroups;
    int w0 = 0;
    for (int g = 0; g < ngroups; g++) {
        int cw = gbase + (g < grem ? 1 : 0);
        agg_gemm8<0><<<dim3(16, 8, cw), 512, 0, stream>>>(XT, adjb, Wt, fcb, P1, w0, 0, 4096, 0);
        agg_gemm8<1><<<dim3(16, 8, cw), 512, 0, stream>>>(P1, adjb, Wt, fcb, P2, w0, 0, 4096, 1);
        agg_gemm8<1><<<dim3(4, 8, cw), 512, 0, stream>>>(P2, adjb, Wt, fcb, P3, w0, 1024, 1024, 2);
        final_add<<<dim3(16, 32, cw), 256, 0, stream>>>(P1, P2, P3, out, w0);
        w0 += cw;
    }
}